// Round 12
// baseline (182.970 us; speedup 1.0000x reference)
//
#include <hip/hip_runtime.h>
#include <hip/hip_bf16.h>
#include <stdint.h>

// x: [16,128,56,56] f32, w: [256,128,3,3] f32, bias: [256] f32
// out: [16,256,56,56] f32
// Implicit GEMM: M=Cout=256, N=pixels=50176, K = (kh*3+kw, c) = 1152
// Round 12: 2D pixel tiles. N64 = 8x8 spatial tile -> patch = 10x10 padded
// pixels = 100 rows x 256 B = 25.6 KB LDS (2D halo reuse; was 48 KB) ->
// 6 blocks/CU (VGPR 84 -> 6 waves/SIMD, exact fit). R11 lesson: per-step
// working set must fit under the allocator's ~84-VGPR preference; latency
// hiding must come from independent blocks (TLP), not deeper ILP. Keep
// R10's step shape (8 A-loads + 8 ds_reads + 32 MFMA, BK=64) which measured
// 84 VGPR. 7x7 tiles x 16 images = 784 blocks, no boundary crossing.

typedef __attribute__((ext_vector_type(8))) short short8;
typedef __attribute__((ext_vector_type(4))) float floatx4;

__device__ static inline void gload_lds16(const void* g, void* l) {
  typedef const __attribute__((address_space(1))) unsigned int* gp_t;
  typedef __attribute__((address_space(3))) unsigned int* lp_t;
  __builtin_amdgcn_global_load_lds((gp_t)(uintptr_t)g, (lp_t)(uint32_t)(uintptr_t)l,
                                   16, 0, 0);
}

// ---------- fused pre-pass: NCHW f32 -> padded NHWC bf16 (halo zeroed)
//   + weight f32 -> bf16 in MFMA-frag order wt2[g=m/16][kq][ch][ks][q][r][e]
//   byte strides: r=16, q=256, ks=1024, ch=2048, kq=4096, g=36864 ----------
__global__ __launch_bounds__(256)
void pre_kernel(const float* __restrict__ x, const float* __restrict__ wsrc,
                __hip_bfloat16* __restrict__ xp, __hip_bfloat16* __restrict__ wt) {
  const int b = blockIdx.x;
  if (b < 16 * 58) {
    const int n = b / 58, hp = b % 58;
    __hip_bfloat16* dst = xp + (size_t)(n * 58 + hp) * 58 * 128;
    if (hp == 0 || hp == 57) {
      const uint4 z = {0, 0, 0, 0};
      uint4* p = (uint4*)dst;
      for (int i = threadIdx.x; i < 928; i += 256) p[i] = z;
      return;
    }
    const int h = hp - 1;
    __shared__ float tile[128][57];
    const float* src = x + (size_t)n * (128 * 3136) + h * 56;
    for (int i = threadIdx.x; i < 128 * 14; i += 256) {
      const int c = i / 14, q = i - c * 14;
      const float4 v = ((const float4*)(src + (size_t)c * 3136))[q];
      tile[c][4 * q + 0] = v.x;
      tile[c][4 * q + 1] = v.y;
      tile[c][4 * q + 2] = v.z;
      tile[c][4 * q + 3] = v.w;
    }
    __syncthreads();
    if (threadIdx.x < 32) {
      const uint4 z = {0, 0, 0, 0};
      const int col = (threadIdx.x >> 4) * 57;
      ((uint4*)(dst + (size_t)col * 128))[threadIdx.x & 15] = z;
    }
    __hip_bfloat16* di = dst + 128;
    for (int i = threadIdx.x; i < 56 * 16; i += 256) {
      const int w = i >> 4, c8 = (i & 15) * 8;
      union { uint4 u; __hip_bfloat16 hh[8]; } pk;
#pragma unroll
      for (int j = 0; j < 8; ++j) pk.hh[j] = __float2bfloat16(tile[c8 + j][w]);
      *(uint4*)(di + (size_t)w * 128 + c8) = pk.u;
    }
  } else {
    const int base = (b - 928) * 256 + threadIdx.x;
    for (int t = base; t < 256 * 9 * 128; t += 36 * 256) {
      const int e = t & 7;
      const int rr = (t >> 3) & 15;
      const int q = (t >> 7) & 3;
      const int ks = (t >> 9) & 1;
      const int ch = (t >> 10) & 1;
      const int t11 = t >> 11;
      const int kq = t11 % 9;
      const int g = t11 / 9;
      const int cout = g * 16 + rr;
      const int c = ch * 64 + ks * 32 + q * 8 + e;
      wt[t] = __float2bfloat16(wsrc[(size_t)(cout * 128 + c) * 9 + kq]);
    }
  }
}

// ---------- main implicit-GEMM MFMA kernel ----------
// 256 thr = 4 waves; wave = M64 (m-groups wave*4 .. wave*4+3), all share the
// 8x8 pixel tile. LDS: patch 100 rows x 256 B = 25.6 KB, staged once.
// Patch row = 16 x 16B chunks, chunk c at slot c ^ (row&7) (verified R1-R11).
// Local indexing: pixel idx = lh*8+lw; tap (kh,kw) reads row (lh+kh)*10+(lw+kw).
__global__ __launch_bounds__(256, 4)
void conv_gemm_kernel(const __hip_bfloat16* __restrict__ xp,
                      const __hip_bfloat16* __restrict__ wt,
                      const float* __restrict__ bias,
                      float* __restrict__ out) {
  __shared__ __align__(16) char smem[25600];

  const int tid = threadIdx.x;
  const int lane = tid & 63;
  const int wave = tid >> 6;  // 0..3 -> Cout base wave*64
  const int col = lane & 15;
  const int quad = lane >> 4;

  // XCD-contiguous tiles: 784 = 8 XCD x 98 tiles (8x8 pixels each)
  const int id = blockIdx.x;
  const int xcd = id & 7;
  const int r = id >> 3;
  const int t = xcd * 98 + r;          // 0..783
  const int nimg = t / 49;
  const int ti = t - nimg * 49;
  const int th = ti / 7;
  const int tw = ti - th * 7;
  const int h0 = th * 8, w0 = tw * 8;  // output tile origin

  // patch origin: padded (h0, w0) — tap (kh,kw) for out (h,w) reads padded
  // (h+kh, w+kw); patch covers padded rows/cols [h0..h0+9] (48+9=57 < 58: OK)
  const char* pbase = (const char*)xp +
                      ((size_t)(nimg * 58 + h0) * 58 + w0) * 256;

  // ---- stage patch: 100 rows x 256 B = 1600 chunks, 6.25 rounds x 256 ----
#pragma unroll
  for (int i = 0; i < 7; ++i) {
    if (i < 6 || tid < 64) {           // wave-uniform guard (round 6: wave 0)
      const int j = i * 256 + tid;     // dest chunk index 0..1599
      const int row = j >> 4;          // 0..99
      const int hh = row / 10;
      const int ww = row - hh * 10;
      const int slot = j & 15;
      const int srcb = (slot ^ (row & 7)) << 4;
      gload_lds16(pbase + (hh * 58 + ww) * 256 + srcb,
                  smem + i * 4096 + wave * 1024);
    }
  }

  // ---- A-frag base pointers: wt2 + g*36864B + lane*16, g = wave*4 + mt ----
  const char* wtb = (const char*)wt;
  const char* pA = wtb + (size_t)(wave * 4) * 36864 + lane * 16;
  // frag byte offset(kq,ch,ks) = kq*4096 + ch*2048 + ks*1024; mt stride 36864

  // ---- per-lane patch row bases (tap (0,0)) + output pixel offsets ----
  int rbase[4], pixofs[4];
#pragma unroll
  for (int nt = 0; nt < 4; ++nt) {
    const int idx = nt * 16 + col;     // 0..63 within the 8x8 tile
    const int lh = idx >> 3;
    const int lw = idx & 7;
    rbase[nt] = lh * 10 + lw;          // patch row at tap (0,0)
    pixofs[nt] = (h0 + lh) * 56 + (w0 + lw);
  }

  floatx4 acc[4][4];
#pragma unroll
  for (int a = 0; a < 4; ++a)
#pragma unroll
    for (int c = 0; c < 4; ++c) acc[a][c] = (floatx4)0.f;

  __syncthreads();  // patch ready (drains staging vmcnt)

  // ---- K loop: 18 steps (9 taps x 2 ch-halves), BK=64, NO barriers ----
#pragma unroll
  for (int s = 0; s < 18; ++s) {
    const int kq = s >> 1, ch = s & 1;
    const int kh = kq / 3;
    const int tofs = kh * 10 + (kq - kh * 3);  // patch-row delta for this tap
    const int aofs = kq * 4096 + ch * 2048;

    short8 af[4][2];  // [mt][ks] from L2 (frag-ordered wt2): 8 loads
#pragma unroll
    for (int mt = 0; mt < 4; ++mt)
#pragma unroll
      for (int ks = 0; ks < 2; ++ks)
        af[mt][ks] = *(const short8*)(pA + mt * 36864 + aofs + ks * 1024);

    short8 bf[4][2];  // [nt][ks] from LDS patch: 8 ds_read_b128
#pragma unroll
    for (int nt = 0; nt < 4; ++nt) {
      const int rowB = rbase[nt] + tofs;
#pragma unroll
      for (int ks = 0; ks < 2; ++ks) {
        const int cB = ch * 8 + ks * 4 + quad;
        const int pos = cB ^ (rowB & 7);
        bf[nt][ks] = *(const short8*)(smem + rowB * 256 + (pos << 4));
      }
    }

#pragma unroll
    for (int ks = 0; ks < 2; ++ks)
#pragma unroll
      for (int mt = 0; mt < 4; ++mt)
#pragma unroll
        for (int nt = 0; nt < 4; ++nt)
          acc[mt][nt] = __builtin_amdgcn_mfma_f32_16x16x32_bf16(
              af[mt][ks], bf[nt][ks], acc[mt][nt], 0, 0, 0);
  }

  // ---- epilogue: bias + store (C/D: row m=quad*4+rr, col n=lane&15) ----
#pragma unroll
  for (int nt = 0; nt < 4; ++nt) {
    float* op = out + (size_t)nimg * (256 * 3136) + pixofs[nt];
#pragma unroll
    for (int mt = 0; mt < 4; ++mt) {
      const int mb = wave * 64 + mt * 16 + quad * 4;
#pragma unroll
      for (int rr = 0; rr < 4; ++rr) {
        op[(size_t)(mb + rr) * 3136] = acc[mt][nt][rr] + bias[mb + rr];
      }
    }
  }
}

// ---------- fallback: direct fp32 conv (only if ws too small) ----------
__global__ __launch_bounds__(256)
void direct_conv_kernel(const float* __restrict__ x, const float* __restrict__ wgt,
                        const float* __restrict__ bias, float* __restrict__ out) {
  const long t = (long)blockIdx.x * 256 + threadIdx.x;
  if (t >= 16L * 256 * 3136) return;
  const int w = t % 56;
  const int h = (t / 56) % 56;
  const int o = (t / 3136) % 256;
  const int n = t / (256L * 3136);
  float s = bias[o];
  for (int c = 0; c < 128; ++c)
    for (int kh = 0; kh < 3; ++kh) {
      const int hh = h + kh - 1;
      if (hh < 0 || hh >= 56) continue;
      for (int kw = 0; kw < 3; ++kw) {
        const int ww = w + kw - 1;
        if (ww < 0 || ww >= 56) continue;
        s += x[((size_t)(n * 128 + c) * 56 + hh) * 56 + ww] *
             wgt[((size_t)(o * 128 + c) * 3 + kh) * 3 + kw];
      }
    }
  out[t] = s;
}

extern "C" void kernel_launch(void* const* d_in, const int* in_sizes, int n_in,
                              void* d_out, int out_size, void* d_ws, size_t ws_size,
                              hipStream_t stream) {
  const float* x = (const float*)d_in[0];
  const float* w = (const float*)d_in[1];
  const float* b = (const float*)d_in[2];
  float* out = (float*)d_out;

  const size_t xp_bytes = (size_t)16 * 58 * 58 * 128 * 2;  // 13,778,944
  const size_t wt_bytes = (size_t)256 * 9 * 128 * 2;       //    589,824
  // All patch reads are in-bounds (tile 48+9 = 57 < 58); no overflow slack
  // needed.

  if (ws_size >= xp_bytes + wt_bytes) {
    __hip_bfloat16* xp = (__hip_bfloat16*)d_ws;
    __hip_bfloat16* wt = (__hip_bfloat16*)((char*)d_ws + xp_bytes);
    hipLaunchKernelGGL(pre_kernel, dim3(16 * 58 + 36), dim3(256), 0, stream,
                       x, w, xp, wt);
    hipLaunchKernelGGL(conv_gemm_kernel, dim3(784), dim3(256), 0, stream,
                       xp, wt, b, out);
  } else {
    const long total = 16L * 256 * 3136;
    hipLaunchKernelGGL(direct_conv_kernel, dim3((unsigned)((total + 255) / 256)),
                       dim3(256), 0, stream, x, w, b, out);
  }
}